// Round 13
// baseline (23.980 us; speedup 1.0000x reference)
//
#include <hip/hip_runtime.h>

// ---------------------------------------------------------------------------
// FFT_Conv_Layer == 3x3 "same" spatial conv with flipped REAL filter plane:
//   out[b,o,y,x] = sum_{i,ky,kx} filts[0,i,o,ky,kx,0] * img[b,i,y+1-ky,x+1-kx]
//
// Ladder: R2 22.54 | R5 27.0 (1 w/SIMD) | R7 21.24 (+XCD swz) | R8 21.07 |
//         R9 21.10 (4 w/SIMD) | R10 21.55 (cross-tile pipe) — all neutral.
// Invariant across all: ~8.4M in-conv f32->f16 converts (+scalar loads +
// ds_writes) ~= 10us of SIMD issue — the real wall. R11/R12: convert ONCE in
// a prep kernel (pkrtz, channels-last, chunk-XOR-preswizzled pimg in d_ws),
// conv stages via global_load_lds (zero staging VALU), K-loop = R7 verbatim.
// (R12's bench was lost to an unresponsive container; resubmitted unchanged.)
// ---------------------------------------------------------------------------

typedef _Float16 f16x8 __attribute__((ext_vector_type(8)));
typedef __fp16   fp16x2 __attribute__((ext_vector_type(2)));
typedef float    f32x4 __attribute__((ext_vector_type(4)));

#define NB 16
#define NC 64
#define NH 64
#define NW 64
#define CHUNKS 528                  // 66 xp * 8 ci chunks (16B) per row
#define SLAB_BYTES (CHUNKS * 16)    // 8448 B per pimg row
#define SLAB_HALFS (CHUNKS * 8)     // 4224 halfs
#define LDS_SLAB 9216               // LDS slab stride (pad for DMA tail)
#define PIMG_ROWS (NB * 66 + 1)     // +1 slack row: 9-call DMA tail overrun
#define WF_HALFS (9 * 2 * 4 * 64 * 8)   // 36,864

typedef __attribute__((address_space(3))) unsigned int lds_u32;
typedef __attribute__((address_space(1))) const unsigned int gbl_u32;

// ---------------------------------------------------------------------------
// prep: 1200 blocks.
//  bid < 1056: (b, yp) — one pimg row. Interior (yp=1..64): wave w loads
//    channels w*16..w*16+15 at x=lane (coalesced 256B/instr), cvt_pkrtz,
//    2 swizzled global f16x8 writes: chunk = xp*8 + (ci^(xp&7)). tid<16
//    zero the xp=0,65 pad chunks. Border rows (yp=0,65): all-zero.
//  bid >= 1056: weight fragments (old prep_w):
//    Wf[t][kc][n][lane][e] = filts[0][kc*32+(l/16)*8+e][n*16+l%16][ky][kx][0]
// ---------------------------------------------------------------------------
__global__ __launch_bounds__(256) void prep(const float* __restrict__ imgs,
                                            const float* __restrict__ filts,
                                            _Float16* __restrict__ pimg,
                                            _Float16* __restrict__ wf) {
    const int bid = blockIdx.x;
    const int tid = threadIdx.x;
    if (bid < NB * 66) {
        const int b  = bid / 66;
        const int yp = bid % 66;
        char* row = (char*)(pimg + (size_t)bid * SLAB_HALFS);
        if (yp == 0 || yp == 65) {
            f16x8 z;
            #pragma unroll
            for (int k = 0; k < 8; ++k) z[k] = (_Float16)0.f;
            for (int c = tid; c < CHUNKS; c += 256)
                *reinterpret_cast<f16x8*>(row + c * 16) = z;
            return;
        }
        const int y = yp - 1;
        const int w = tid >> 6;          // wave: channels w*16 .. w*16+15
        const int l = tid & 63;          // x = l
        if (tid < 16) {                  // zero pads: xp = 0 and 65, ci 0..7
            const int ci  = tid >> 1;
            const int xpp = (tid & 1) ? 65 : 0;
            const int c2  = xpp * 8 + (ci ^ (xpp & 7));
            f16x8 z;
            #pragma unroll
            for (int k = 0; k < 8; ++k) z[k] = (_Float16)0.f;
            *reinterpret_cast<f16x8*>(row + c2 * 16) = z;
        }
        float f[16];
        const float* src = imgs + ((size_t)(b * NC + w * 16)) * NH * NW + (size_t)y * NW + l;
        #pragma unroll
        for (int k = 0; k < 16; ++k) f[k] = src[(size_t)k * NH * NW];
        const int xp = l + 1;
        #pragma unroll
        for (int j = 0; j < 2; ++j) {
            const int ci = w * 2 + j;
            union { f16x8 v; fp16x2 h2[4]; } u;
            #pragma unroll
            for (int p = 0; p < 4; ++p)
                u.h2[p] = __builtin_amdgcn_cvt_pkrtz(f[j * 8 + 2 * p], f[j * 8 + 2 * p + 1]);
            const int chunk = xp * 8 + (ci ^ (xp & 7));
            *reinterpret_cast<f16x8*>(row + chunk * 16) = u.v;
        }
    } else {
        const int f = (bid - NB * 66) * 256 + tid;   // 144*256 = 36,864 exact
        const int e  = f & 7;
        const int l  = (f >> 3) & 63;
        const int n  = (f >> 9) & 3;
        const int kc = (f >> 11) & 1;
        const int t  = f >> 12;
        const int i  = kc * 32 + (l >> 4) * 8 + e;
        const int o  = n * 16 + (l & 15);
        const int ky = t / 3, kx = t % 3;
        wf[f] = (_Float16)filts[(((i * 64 + o) * 3 + ky) * 3 + kx) * 2];
    }
}

// ---------------------------------------------------------------------------
// conv: 512 blocks (XCD-swizzled) = (b, 2-row group), 4 waves (256 thr).
//   Staging: wave w DMAs pimg row yp=y0+w into LDS slab w via 9x
//     global_load_lds dwordx4 (1KB/call, linear dest, swizzle pre-baked in
//     pimg). Tail call reads 768B of the next row -> LDS pad, never read.
//   Compute (R7 verbatim): wave w = (row w>>1, oh w&1): 4x2 16x16 frags,
//     K = 3ky*3kx*2kc: 4 A ds_reads + 2 B global + 8 MFMA per step.
//   C/D layout (m89/m91-verified): o = n*16+(lane&15), x = m*16+(lane>>4)*4+j
// ---------------------------------------------------------------------------
__global__ __launch_bounds__(256, 2) void conv(const _Float16* __restrict__ pimg,
                                               const _Float16* __restrict__ wf,
                                               float* __restrict__ out) {
    __shared__ char lds[4 * LDS_SLAB];   // 36,864 B
    const int bid = blockIdx.x;
    const int swz = ((bid & 7) << 6) | (bid >> 3);   // bijective: 512 = 8*64
    const int b   = swz >> 5;
    const int y0  = (swz & 31) << 1;     // first output row of this block
    const int tid = threadIdx.x;
    const int w   = tid >> 6;            // wave 0..3
    const int l   = tid & 63;
    const int h   = l >> 4;              // k-chunk lane group
    const int r   = l & 15;              // A-row / B-col within fragment

    // ---- stage slab w = pimg row yp = y0 + w (image row y0 + w - 1) ----
    {
        const char* g = (const char*)(pimg + (size_t)(b * 66 + y0 + w) * SLAB_HALFS);
        char* d = lds + w * LDS_SLAB;
        #pragma unroll
        for (int k = 0; k < 9; ++k) {
            __builtin_amdgcn_global_load_lds(
                (gbl_u32*)(g + k * 1024 + l * 16),
                (lds_u32*)(d + k * 1024), 16, 0, 0);
        }
    }
    __syncthreads();

    const int row = w >> 1;              // output row offset within group
    const int oh  = w & 1;               // outC half (0..1)

    f32x4 acc[4][2];
    #pragma unroll
    for (int m = 0; m < 4; ++m)
        #pragma unroll
        for (int n = 0; n < 2; ++n)
            acc[m][n] = f32x4{0.f, 0.f, 0.f, 0.f};

    #pragma unroll
    for (int ky = 0; ky < 3; ++ky) {
        const char* slab = lds + (row + 2 - ky) * LDS_SLAB;   // rs in 0..3
        #pragma unroll
        for (int kx = 0; kx < 3; ++kx) {
            const _Float16* wft = wf + (size_t)(ky * 3 + kx) * (2 * 4 * 64 * 8);
            #pragma unroll
            for (int kc = 0; kc < 2; ++kc) {
                f16x8 a[4], bb[2];
                #pragma unroll
                for (int m = 0; m < 4; ++m) {
                    const int xp = m * 16 + r + 2 - kx;          // 0..65
                    const int chunk = xp * 8 + (((kc << 2) + h) ^ (xp & 7));
                    a[m] = *reinterpret_cast<const f16x8*>(slab + chunk * 16);
                }
                #pragma unroll
                for (int n = 0; n < 2; ++n)
                    bb[n] = *reinterpret_cast<const f16x8*>(
                        wft + ((size_t)((kc << 2) + (oh * 2 + n)) * 64 + l) * 8);
                #pragma unroll
                for (int m = 0; m < 4; ++m)
                    #pragma unroll
                    for (int n = 0; n < 2; ++n)
                        acc[m][n] = __builtin_amdgcn_mfma_f32_16x16x32_f16(a[m], bb[n], acc[m][n], 0, 0, 0);
            }
        }
    }

    const int y = y0 + row;
    #pragma unroll
    for (int m = 0; m < 4; ++m) {
        const int x0 = m * 16 + h * 4;
        #pragma unroll
        for (int n = 0; n < 2; ++n) {
            const int o = oh * 32 + n * 16 + r;
            *reinterpret_cast<f32x4*>(out + (((size_t)(b * 64 + o) * 64 + y) * 64) + x0) = acc[m][n];
        }
    }
}

extern "C" void kernel_launch(void* const* d_in, const int* in_sizes, int n_in,
                              void* d_out, int out_size, void* d_ws, size_t ws_size,
                              hipStream_t stream) {
    const float* imgs  = (const float*)d_in[0];   // [16][64][64][64] f32
    const float* filts = (const float*)d_in[1];   // [1][64][64][3][3][2] f32
    float* out = (float*)d_out;                   // [16][64][64][64] f32

    _Float16* pimg = (_Float16*)d_ws;             // 8,929,536 B (incl. slack)
    _Float16* wfb  = pimg + (size_t)PIMG_ROWS * SLAB_HALFS;  // + 73,728 B

    hipLaunchKernelGGL(prep, dim3(NB * 66 + WF_HALFS / 256), dim3(256), 0, stream,
                       imgs, filts, pimg, wfb);
    hipLaunchKernelGGL(conv, dim3(NB * 32), dim3(256), 0, stream, pimg, wfb, out);
}